// Round 12
// baseline (104.542 us; speedup 1.0000x reference)
//
#include <hip/hip_runtime.h>
#include <math.h>

#define DIM 128
#define N_PTS 512
#define K_NEIGH 16
#define POS_HID 64
#define ATTN_HID 512

typedef __attribute__((ext_vector_type(8))) short short8;
typedef __attribute__((ext_vector_type(4))) float f32x4;
typedef unsigned short us;
typedef unsigned long long ull;

__device__ __forceinline__ us f2b(float f) {
    unsigned int u = __builtin_bit_cast(unsigned int, f);
    u += 0x7fffu + ((u >> 16) & 1u);          // RNE
    return (us)(u >> 16);
}

__device__ __forceinline__ ull shflx64(ull v, int m) {
    int lo = __shfl_xor((int)(unsigned int)v, m);
    int hi = __shfl_xor((int)(unsigned int)(v >> 32), m);
    return ((ull)(unsigned int)hi << 32) | (unsigned int)lo;
}

// ---------------------------------------------------------------------------
// Kernel A [R9, verified 99.14]: qkv + pack merged.
// Blocks 0..npts/4-1: qkv tiles with inline wqkv->bf16 fragments.
// Blocks npts/4.. : pack aw1/aw2/pw2 -> p1/p2/p3 [R2-proven layout:
// B[k][n] -> lane l=(k/8%4)*16+(n%16), elem j=k%8, frag ks*NT+nt].
// ---------------------------------------------------------------------------
__global__ __launch_bounds__(256)
void qkv_pack_kernel(const float* __restrict__ x,
                     const float* __restrict__ wqkv,
                     const float* __restrict__ aw1,
                     const float* __restrict__ aw2,
                     const float* __restrict__ pw2,
                     float* __restrict__ qkv,
                     us* __restrict__ p1, us* __restrict__ p2,
                     us* __restrict__ p3, int npts) {
    __shared__ __align__(16) us xA[16][136];
    const int tid = threadIdx.x;
    const int nq = npts >> 2;

    if ((int)blockIdx.x >= nq) {
        int t = ((int)blockIdx.x - nq) * 256 + tid;
        if (t < 65536) {                        // aw1: ks 0..3, nt 0..31
            int j = t & 7, l = (t >> 3) & 63, nt = (t >> 9) & 31, ks = t >> 14;
            int k = ks * 32 + (l >> 4) * 8 + j, n = nt * 16 + (l & 15);
            p1[t] = f2b(aw1[k * ATTN_HID + n]);
        } else if (t < 131072) {                // aw2: ch 0..15, nt 0..7
            int u = t - 65536;
            int j = u & 7, l = (u >> 3) & 63, nt = (u >> 9) & 7, ch = u >> 12;
            int k = ch * 32 + (l >> 4) * 8 + j, n = nt * 16 + (l & 15);
            p2[u] = f2b(aw2[k * DIM + n]);
        } else if (t < 139264) {                // pw2: ks 0..1, nt 0..7
            int u = t - 131072;
            int j = u & 7, l = (u >> 3) & 63, nt = (u >> 9) & 7, ks = u >> 12;
            int k = ks * 32 + (l >> 4) * 8 + j, n = nt * 16 + (l & 15);
            p3[u] = f2b(pw2[k * DIM + n]);
        }
        return;
    }

    const int w = tid >> 6, lane = tid & 63, quad = lane >> 4, lq = lane & 15;
    const int n0 = ((int)blockIdx.x >> 2) * 16;
    const int ntb = ((int)blockIdx.x & 3) * 6;
    const int b = n0 >> 9, nn = n0 & (N_PTS - 1);
#pragma unroll
    for (int rr = 0; rr < 8; ++rr) {
        int id = rr * 256 + tid;
        int d = id >> 4, i = id & 15;
        xA[i][d] = f2b(x[(size_t)(b * DIM + d) * N_PTS + nn + i]);
    }
    __syncthreads();
    short8 a[4];
#pragma unroll
    for (int ks = 0; ks < 4; ++ks)
        a[ks] = *(const short8*)&xA[lq][ks * 32 + quad * 8];
#pragma unroll
    for (int i = 0; i < 2; ++i) {
        int nl = w + i * 4;
        if (nl < 6) {
            int nt = ntb + nl;
            f32x4 acc = {0.f, 0.f, 0.f, 0.f};
#pragma unroll
            for (int ks = 0; ks < 4; ++ks) {
                const float* wp = wqkv + (size_t)(ks * 32 + quad * 8) * 384 + nt * 16 + lq;
                short8 bf;
#pragma unroll
                for (int j = 0; j < 8; ++j) bf[j] = (short)f2b(wp[(size_t)j * 384]);
                acc = __builtin_amdgcn_mfma_f32_16x16x32_bf16(a[ks], bf, acc, 0, 0, 0);
            }
#pragma unroll
            for (int r = 0; r < 4; ++r)
                qkv[(size_t)(n0 + quad * 4 + r) * 384 + nt * 16 + lq] = acc[r];
        }
    }
}

// ---------------------------------------------------------------------------
// Fused attention [R12]: 2 points/block, 2 WAVES/POINT -> 2 waves/SIMD.
// Fixes for the R2/R3 failures:
//  * top-k runs on ONE wave per point (sub==0) — NO duplicated shfl chains
//    (shfl = ds_bpermute on the CU-shared LDS unit; duplication made R2
//    LDS-throughput-bound). Partner wave issues its hoists and waits.
//  * hoists stay vectorized & early (R3's serial de-hoisted loads avoided).
//  * pe/gather/hin/vg split by d-halves (wave sub owns cols 64*sub..+64);
//    hinA per-point, written disjointly. MLP split 8+8 chunks (R2-verified
//    math). Single-buffered weight loads: at 2 waves/SIMD the partner wave
//    hides load latency (what R8's dbuf did at 1 wave), peak ~180 VGPR.
//  * c2 exchange + split softmax/store = R2's verified epilogue.
// 3 barriers total. launch_bounds(256,2) caps VGPR at 256 (2 blocks/CU).
// ---------------------------------------------------------------------------
__global__ __launch_bounds__(256, 2)
void attn_fused_kernel(const float* __restrict__ pos,
                       const float* __restrict__ qkv,
                       const float* __restrict__ pw1,
                       const float* __restrict__ pb1,
                       const float* __restrict__ pb2,
                       const us* __restrict__ p1,
                       const us* __restrict__ p2,
                       const us* __restrict__ p3,
                       const float* __restrict__ ab1,
                       float* __restrict__ out) {
    __shared__ __align__(16) us hinA[2][16][136];   //  8.7 KB, per-POINT
    __shared__ __align__(16) us h1s[4][16][40];     //  5.1 KB, per-wave
    __shared__ int nbrs[2][16];                     //  128 B, per-point
    __shared__ __align__(16) f32x4 cxch[4][4][64];  // 16 KB, c2 exchange

    const int tid = threadIdx.x;
    const int w = tid >> 6, lane = tid & 63, quad = lane >> 4, lq = lane & 15;
    const int pt = w >> 1, sub = w & 1;
    const int g = blockIdx.x * 2 + pt, b = g >> 9, n = g & (N_PTS - 1);
    const int ch0 = sub << 3;               // this wave's hidden-chunk range

    // ==== hoists (all waves, vectorized, issued before topk/wait) ====
    short8 b3f[2][4];                      // pw2 frags for OWN 4 nt tiles
#pragma unroll
    for (int ks = 0; ks < 2; ++ks)
#pragma unroll
        for (int i = 0; i < 4; ++i)
            b3f[ks][i] = *(const short8*)(p3 + (size_t)((ks * 8 + sub * 4 + i) * 64 + lane) * 8);

    float w1x[2][8], w1y[2][8], w1z[2][8], w1b[2][8];   // pos-MLP layer-1 wts
#pragma unroll
    for (int ks = 0; ks < 2; ++ks)
#pragma unroll
        for (int jj = 0; jj < 8; ++jj) {
            int c = ks * 32 + quad * 8 + jj;
            w1x[ks][jj] = pw1[c];
            w1y[ks][jj] = pw1[64 + c];
            w1z[ks][jj] = pw1[128 + c];
            w1b[ks][jj] = pb1[c];
        }

    float qvr[4], pb2r[4], ab1r[16];
#pragma unroll
    for (int i = 0; i < 4; ++i) {
        int nt = sub * 4 + i;
        qvr[i]  = qkv[(size_t)g * 384 + nt * 16 + lq];
        pb2r[i] = pb2[nt * 16 + lq];
    }
#pragma unroll
    for (int i = 0; i < 16; ++i) ab1r[i] = ab1[(sub * 16 + i) * 16 + lq];

    // ---- top-16 on wave sub==0 ONLY (u64-key butterfly, R5-exact) ----
    if (sub == 0) {
        const float pix = pos[g * 3 + 0], piy = pos[g * 3 + 1], piz = pos[g * 3 + 2];
        float d2[8];
#pragma unroll
        for (int rr = 0; rr < 8; ++rr) {
            int j = rr * 64 + lane;
            float dx = pix - pos[(b * N_PTS + j) * 3 + 0];
            float dy = piy - pos[(b * N_PTS + j) * 3 + 1];
            float dz = piz - pos[(b * N_PTS + j) * 3 + 2];
            d2[rr] = dx * dx + dy * dy + dz * dz;
        }
        for (int r = 0; r < K_NEIGH; ++r) {
            ull key = ~0ULL;
#pragma unroll
            for (int rr = 0; rr < 8; ++rr) {
                unsigned int fb = __builtin_bit_cast(unsigned int, d2[rr]);
                ull k2 = ((ull)fb << 32) | (unsigned int)(rr * 64 + lane);
                key = k2 < key ? k2 : key;
            }
#pragma unroll
            for (int off = 32; off > 0; off >>= 1) {
                ull o = shflx64(key, off);
                key = o < key ? o : key;
            }
            unsigned int jw = (unsigned int)key;      // uniform post-butterfly
            if (lane == 0) nbrs[pt][r] = (int)jw;
            if (lane == (int)(jw & 63)) d2[jw >> 6] = __builtin_inff();
        }
    }
    __syncthreads();

    // ---- pos-MLP hidden (duplicated VALU; k = ks*32 + quad*8 + jj) ----
    short8 pha[2];
    {
        const int jn = nbrs[pt][lq];
        float rx = pos[g * 3 + 0] - pos[(b * N_PTS + jn) * 3 + 0];
        float ry = pos[g * 3 + 1] - pos[(b * N_PTS + jn) * 3 + 1];
        float rz = pos[g * 3 + 2] - pos[(b * N_PTS + jn) * 3 + 2];
#pragma unroll
        for (int ks = 0; ks < 2; ++ks) {
            short8 f;
#pragma unroll
            for (int jj = 0; jj < 8; ++jj) {
                float h = rx * w1x[ks][jj] + ry * w1y[ks][jj] + rz * w1z[ks][jj] + w1b[ks][jj];
                f[jj] = (short)f2b(fmaxf(h, 0.f));
            }
            pha[ks] = f;
        }
    }

    // ---- pe for OWN 4 nt tiles ----
    f32x4 pe[4];
#pragma unroll
    for (int i = 0; i < 4; ++i) {
        f32x4 acc = {0.f, 0.f, 0.f, 0.f};
        acc = __builtin_amdgcn_mfma_f32_16x16x32_bf16(pha[0], b3f[0][i], acc, 0, 0, 0);
        acc = __builtin_amdgcn_mfma_f32_16x16x32_bf16(pha[1], b3f[1][i], acc, 0, 0, 0);
#pragma unroll
        for (int r = 0; r < 4; ++r) pe[i][r] = acc[r] + pb2r[i];
    }

    // ---- gather OWN d-half: hin cols [64*sub,64*sub+64) + vg own tiles ----
    f32x4 vg[4];
    {
        int jr[4];
#pragma unroll
        for (int r = 0; r < 4; ++r) jr[r] = nbrs[pt][quad * 4 + r];
#pragma unroll
        for (int i = 0; i < 4; ++i) {
            int d = (sub * 4 + i) * 16 + lq;
#pragma unroll
            for (int r = 0; r < 4; ++r) {
                const float* kv = qkv + (size_t)(b * N_PTS + jr[r]) * 384;
                float pp = pe[i][r];
                hinA[pt][quad * 4 + r][d] = f2b(qvr[i] - kv[128 + d] + pp);
                vg[i][r] = kv[256 + d] + pp;
            }
        }
    }
    __syncthreads();

    // ---- layer1 + layer2, OWN 8 of 16 hidden chunks (R2-verified split) ----
    short8 a1f[4];
#pragma unroll
    for (int ks = 0; ks < 4; ++ks)
        a1f[ks] = *(const short8*)&hinA[pt][lq][ks * 32 + quad * 8];

    f32x4 c2[8];
#pragma unroll
    for (int nt = 0; nt < 8; ++nt) c2[nt] = (f32x4){0.f, 0.f, 0.f, 0.f};

#pragma unroll
    for (int c = 0; c < 8; ++c) {
        const int ch = ch0 + c;
        short8 p1f[2][4];
#pragma unroll
        for (int t = 0; t < 2; ++t)
#pragma unroll
            for (int ks = 0; ks < 4; ++ks)
                p1f[t][ks] = *(const short8*)(p1 + (size_t)(((ks << 5) + ch * 2 + t) * 64 + lane) * 8);
#pragma unroll
        for (int t = 0; t < 2; ++t) {
            f32x4 acc = {0.f, 0.f, 0.f, 0.f};
#pragma unroll
            for (int ks = 0; ks < 4; ++ks)
                acc = __builtin_amdgcn_mfma_f32_16x16x32_bf16(a1f[ks], p1f[t][ks], acc, 0, 0, 0);
            float bias = ab1r[c * 2 + t];
#pragma unroll
            for (int r = 0; r < 4; ++r)
                h1s[w][quad * 4 + r][t * 16 + lq] = f2b(fmaxf(acc[r] + bias, 0.f));
        }
        short8 p2f[8];
#pragma unroll
        for (int nt2 = 0; nt2 < 8; ++nt2)
            p2f[nt2] = *(const short8*)(p2 + (size_t)(((ch << 3) + nt2) * 64 + lane) * 8);
        const short8 a2 = *(const short8*)&h1s[w][lq][quad * 8];
#pragma unroll
        for (int nt2 = 0; nt2 < 8; ++nt2)
            c2[nt2] = __builtin_amdgcn_mfma_f32_16x16x32_bf16(a2, p2f[nt2], c2[nt2], 0, 0, 0);
    }

    // ---- exchange partial c2 with partner wave (R2-verified epilogue) ----
#pragma unroll
    for (int i = 0; i < 4; ++i)
        cxch[w][i][lane] = c2[(sub ^ 1) * 4 + i];
    __syncthreads();

#pragma unroll
    for (int i = 0; i < 4; ++i) {
        const int nt2 = sub * 4 + i;
        f32x4 o = cxch[w ^ 1][i][lane];
        f32x4 s4 = c2[nt2];
        s4[0] += o[0]; s4[1] += o[1]; s4[2] += o[2]; s4[3] += o[3];

        float m = fmaxf(fmaxf(s4[0], s4[1]), fmaxf(s4[2], s4[3]));
        m = fmaxf(m, __shfl_xor(m, 16));
        m = fmaxf(m, __shfl_xor(m, 32));
        float e0 = __expf(s4[0] - m), e1 = __expf(s4[1] - m);
        float e2 = __expf(s4[2] - m), e3 = __expf(s4[3] - m);
        float s = e0 + e1 + e2 + e3;
        f32x4 v4 = vg[i];
        float a = e0 * v4[0] + e1 * v4[1] + e2 * v4[2] + e3 * v4[3];
        s += __shfl_xor(s, 16); s += __shfl_xor(s, 32);
        a += __shfl_xor(a, 16); a += __shfl_xor(a, 32);
        if (quad == 0)
            out[(size_t)(b * DIM + nt2 * 16 + lq) * N_PTS + n] = a / s;
    }
}

extern "C" void kernel_launch(void* const* d_in, const int* in_sizes, int n_in,
                              void* d_out, int out_size, void* d_ws, size_t ws_size,
                              hipStream_t stream) {
    const float* x    = (const float*)d_in[0];
    const float* pos  = (const float*)d_in[1];
    const float* wqkv = (const float*)d_in[2];
    const float* pw1  = (const float*)d_in[3];
    const float* pb1  = (const float*)d_in[4];
    const float* pw2  = (const float*)d_in[5];
    const float* pb2  = (const float*)d_in[6];
    const float* aw1  = (const float*)d_in[7];
    const float* ab1  = (const float*)d_in[8];
    const float* aw2  = (const float*)d_in[9];
    // ab2 unused: softmax over k is invariant to per-channel bias.
    float* out = (float*)d_out;

    int B = in_sizes[0] / (DIM * N_PTS);
    int npts = B * N_PTS;                    // 1024

    char* ws = (char*)d_ws;
    float* qkv = (float*)ws;                               // npts*384 f32
    us* p1 = (us*)(ws + (size_t)npts * 384 * 4);           // 65536 us
    us* p2 = p1 + 65536;                                   // 65536 us
    us* p3 = p2 + 65536;                                   // 8192 us

    int nq = npts / 4;                       // qkv blocks
    int grid = nq + (139264 + 255) / 256;    // + 544 pack blocks
    qkv_pack_kernel<<<grid, 256, 0, stream>>>(x, wqkv, aw1, aw2, pw2,
                                              qkv, p1, p2, p3, npts);
    attn_fused_kernel<<<npts / 2, 256, 0, stream>>>(pos, qkv,
                                                    pw1, pb1, pb2,
                                                    p1, p2, p3, ab1, out);
}